// Round 1
// 78.316 us; speedup vs baseline: 1.0104x; 1.0104x over previous
//
#include <hip/hip_runtime.h>

// JeffressFilter: T=1024, NC=16 spatial channels, 2 in-features, D_OUT=512 taps.
// out[t,nc,d] = w[d] * ( [t>=dl0]*y[t-dl0, nc, 0] + [t>=dl1]*y[t-dl1, nc, 1] )
// y = leaky-integrator scan of x (decay = exp(-1/2)).
//
// R5: restructure both kernels around latency, not just traffic.
//  - Scan: 64 chunks x 16 steps, 64-step warm-up (truncation exp(-32)=1.3e-14,
//    identical to R4 which verified absmax 0.0). 32 blocks x 64 threads, ALL
//    lanes active (R4 had tid<32 masked -> 8 effective waves chip-wide),
//    serial chain 128 -> 80 steps, x-loads coalesced 128B per segment.
//  - Gather: delay is linear in d, so with d UNIT-STRIDE across lanes every
//    load is a broadcast or a contiguous 256B segment (sliding window), vs
//    R4's 16B-strided lanes (16 cache lines per wave-load). One wave per
//    (t,nc) row: 16384 waves (4x R4) for latency hiding. Stores contiguous.
//    Pad region supplies the t<delay zeros -> mask free, no branches, no LDS.

#define T_LEN  1024
#define D_OUT  512
#define NC     16
#define PAD    256
#define ROW    (PAD + T_LEN)    // 1280 floats per row
#define YB_OFF (NC * ROW)       // second feature plane

// ---------------------------------------------------------------------------
// Kernel 1: zero the pads + chunked LIF scan into transposed ws.
// 32 blocks x 64 threads. Thread (b, tid): ch = tid&31 (coalesced x reads),
// chunk = b*2 + (tid>>5). 64-step warm-up + 16 stored steps.
// ---------------------------------------------------------------------------
__global__ __launch_bounds__(64) void lif_scan_kernel(const float* __restrict__ x,
                                                      float* __restrict__ ws) {
    const int tid = threadIdx.x;   // 0..63
    const int b   = blockIdx.x;    // 0..31

    // zero the 32 row-pads (32*256 = 8192 floats; 4 per thread)
    #pragma unroll
    for (int k = 0; k < 4; ++k) {
        const int id = (b * 64 + tid) * 4 + k;   // 0..8191
        const int r  = id >> 8;                  // row 0..31
        const int c  = id & 255;                 // pad col 0..255
        ws[r * ROW + c] = 0.0f;
    }

    const int ch    = tid & 31;          // nc*2 + i ; consecutive lanes -> coalesced
    const int chunk = b * 2 + (tid >> 5);   // 0..63
    const int nc    = ch >> 1;
    const int i     = ch & 1;
    float* row = ws + (i ? YB_OFF : 0) + nc * ROW + PAD;

    const int   t0    = chunk * 16;
    const float decay = 0.60653065971263342f;  // exp(-0.5)

    float v = 0.0f;
    #pragma unroll 16
    for (int k = 0; k < 64; ++k) {             // warm-up (exact for chunk 0)
        const int t = t0 - 64 + k;
        const float xv = (t >= 0) ? x[t * 32 + ch] : 0.0f;
        v = decay * v + xv;
    }
    #pragma unroll
    for (int k = 0; k < 16; ++k) {             // stored steps
        const int t = t0 + k;
        v = decay * v + x[t * 32 + ch];
        row[t] = v;
    }
}

// ---------------------------------------------------------------------------
// Kernel 2: one wave per (t, nc) output row of 512 taps.
// d = g*64 + lane  ->  delay/weight loads unit-stride (512B / 256B segments),
// y-window loads unit-stride or broadcast (delay linear in d), stores 256B
// contiguous per wave, 8KB contiguous per block. 4096 blocks x 256 threads.
// ---------------------------------------------------------------------------
__global__ __launch_bounds__(256) void jeffress_kernel(const float* __restrict__ ws,
                                                       const float* __restrict__ w,
                                                       const int2* __restrict__ delay,
                                                       float* __restrict__ out) {
    const int wid  = blockIdx.x * 4 + (threadIdx.x >> 6);  // 0..16383
    const int lane = threadIdx.x & 63;
    const int t    = wid >> 4;        // 0..1023
    const int nc   = wid & 15;        // 0..15

    const float* A = ws + nc * ROW + PAD;      // feature 0 row
    const float* B = A + YB_OFF;               // feature 1 row
    float* orow = out + ((size_t)(t * NC + nc)) * D_OUT;

    #pragma unroll
    for (int g = 0; g < 8; ++g) {
        const int d  = g * 64 + lane;
        const int2 e = delay[d];               // coalesced 512B segment
        const float u0 = A[t - e.x];           // broadcast or unit-stride window
        const float u1 = B[t - e.y];           // (negative idx lands in zero pad)
        orow[d] = w[d] * (u0 + u1);            // coalesced 256B store
    }
}

extern "C" void kernel_launch(void* const* d_in, const int* in_sizes, int n_in,
                              void* d_out, int out_size, void* d_ws, size_t ws_size,
                              hipStream_t stream) {
    const float* x      = (const float*)d_in[0];   // (1024,4,4,2) fp32
    const float* weight = (const float*)d_in[1];   // (512,) fp32
    const int*   delay  = (const int*)d_in[2];     // (512,2) int32
    float* out = (float*)d_out;                    // (1024,4,4,512) fp32
    float* ws  = (float*)d_ws;                     // 40960 floats used

    lif_scan_kernel<<<32, 64, 0, stream>>>(x, ws);

    jeffress_kernel<<<(T_LEN * NC) / 4, 256, 0, stream>>>(
        ws, weight, (const int2*)delay, (float4*)out ? (float*)out : (float*)out);
}

// Round 2
// 77.286 us; speedup vs baseline: 1.0239x; 1.0133x over previous
//
#include <hip/hip_runtime.h>

// JeffressFilter: T=1024, NC=16 spatial channels, 2 in-features, D_OUT=512 taps.
// out[t,nc,d] = w[d] * ( [t>=dl0]*y[t-dl0, nc, 0] + [t>=dl1]*y[t-dl1, nc, 1] )
// y = leaky-integrator scan of x (decay = exp(-1/2)).
//
// R6: FUSED single kernel. R5 showed dur_us is dominated by harness-fixed
// costs (256MiB poison fill ~43us visible in profile); the only remaining
// controllable costs are the second launch and the ws round-trip. Exploit
// decay^64 = e^-32 = 1.3e-14 (same truncation R4/R5 verified at absmax 0.0):
// each block recomputes the y-window it needs locally in LDS.
//
// Block = (t-tile of 16) x (one nc). Needs y[t0-256 .. t0+15] for 2 channels
// = 2x272 floats = 2.2KB LDS.
//   Phase 1 (64 lanes): 32 chunks x 2 ch, chunk len 9, 64-step warm-up.
//     Chain = 73 steps. x reads: thread pairs read 8B contiguous; 4 blocks/CU
//     share the same t-range (consecutive bids = same tile, different nc) so
//     L1 merges the column reads into full lines.
//   Phase 2 (all 256): 4 waves x 4 t. lane = d within 64-group -> delay is
//     linear in d, so LDS reads are broadcast (free) + unit-stride
//     (2 lanes/bank = free); stores 256B contiguous per wave-instruction.
// No ws usage at all; y for t<0 is naturally 0 (zero-init + zero x) so the
// t<delay mask is free.

#define T_LEN  1024
#define D_OUT  512
#define NC     16
#define TT     16            // t-tile per block
#define WIN    (256 + TT)    // 272-float y window per channel
#define WARM   64            // exp(-32) truncation, verified absmax 0.0

__global__ __launch_bounds__(256) void jeffress_fused(const float* __restrict__ x,
                                                      const float* __restrict__ w,
                                                      const int2* __restrict__ delay,
                                                      float* __restrict__ out) {
    __shared__ float yl[2][WIN];

    const int bid = blockIdx.x;
    const int nc  = bid & 15;          // consecutive bids share t-range -> L1 reuse
    const int t0  = (bid >> 4) * TT;
    const int tid = threadIdx.x;
    const int lane = tid & 63;
    const int wv   = tid >> 6;

    // preload per-lane taps/weights for phase 2 (before the barrier, hides latency)
    int2  e[8];
    float wr[8];
    #pragma unroll
    for (int g = 0; g < 8; ++g) {
        const int d = g * 64 + lane;
        e[g]  = delay[d];
        wr[g] = w[d];
    }

    // ---- Phase 1: block-local LIF scan into LDS -------------------------
    if (tid < 64) {
        const int c  = tid >> 1;        // chunk 0..31
        const int i  = tid & 1;         // feature
        const int ch = nc * 2 + i;
        const int p0 = c * 9;           // window position of chunk start
        const int tb = t0 - 256 + p0;   // global t of chunk start
        const float decay = 0.60653065971263342f;  // exp(-0.5)

        float v = 0.0f;
        #pragma unroll 16
        for (int j = 0; j < WARM; ++j) {
            const int t = tb - WARM + j;
            v = decay * v + ((t >= 0 && t < T_LEN) ? x[t * 32 + ch] : 0.0f);
        }
        #pragma unroll
        for (int k = 0; k < 9; ++k) {
            const int t = tb + k;
            v = decay * v + ((t >= 0 && t < T_LEN) ? x[t * 32 + ch] : 0.0f);
            const int p = p0 + k;
            if (p < WIN) yl[i][p] = v;  // stride-9 across chunks: coprime to 32 banks
        }
    }
    __syncthreads();

    // ---- Phase 2: gather + weight, straight to global -------------------
    #pragma unroll
    for (int k = 0; k < 4; ++k) {
        const int ts   = wv * 4 + k;    // 0..15 within tile
        const int t    = t0 + ts;
        const int base = ts + 256;      // LDS index of y[t]
        float* orow = out + ((size_t)(t * NC + nc)) * D_OUT;
        #pragma unroll
        for (int g = 0; g < 8; ++g) {
            // d = g*64+lane: one of {e.x, e.y} is 0 (broadcast), the other is
            // linear in d (unit-stride window). base - e in [0, WIN) always.
            const float u0 = yl[0][base - e[g].x];
            const float u1 = yl[1][base - e[g].y];
            orow[g * 64 + lane] = wr[g] * (u0 + u1);
        }
    }
}

extern "C" void kernel_launch(void* const* d_in, const int* in_sizes, int n_in,
                              void* d_out, int out_size, void* d_ws, size_t ws_size,
                              hipStream_t stream) {
    const float* x      = (const float*)d_in[0];   // (1024,4,4,2) fp32
    const float* weight = (const float*)d_in[1];   // (512,) fp32
    const int*   delay  = (const int*)d_in[2];     // (512,2) int32
    float* out = (float*)d_out;                    // (1024,4,4,512) fp32
    (void)d_ws; (void)ws_size;

    const int nblocks = (T_LEN / TT) * NC;         // 1024
    jeffress_fused<<<nblocks, 256, 0, stream>>>(x, weight, (const int2*)delay, out);
}